// Round 7
// baseline (469.837 us; speedup 1.0000x reference)
//
#include <hip/hip_runtime.h>

typedef float f32x4 __attribute__((ext_vector_type(4)));
typedef float f32x16 __attribute__((ext_vector_type(16)));
typedef unsigned char uchar;
typedef long i64;

#define KEPS 1e-8f
#define BM 128
#define BN 128
#define BK 64    // fp8 bytes == elements; 16 K-iterations over D=1024

// ---------------- 1) row L2-normalize: fp32 norms + fp8 e4m3 copy -----------
__global__ __launch_bounds__(256) void k_normalize(
    const float* __restrict__ in, uchar* __restrict__ xq,
    float* __restrict__ norms, unsigned long long* __restrict__ best,
    float* __restrict__ psum, int D)
{
    const int row = blockIdx.x;
    const int t = threadIdx.x;
    const float4* inr = (const float4*)(in + (size_t)row * D);
    float4 v = inr[t];                       // D=1024 -> 256 float4
    float ss = v.x*v.x + v.y*v.y + v.z*v.z + v.w*v.w;
    for (int off = 32; off; off >>= 1) ss += __shfl_down(ss, off);
    __shared__ float red[4];
    const int lane = t & 63, wave = t >> 6;
    if (lane == 0) red[wave] = ss;
    __syncthreads();
    const float total = red[0] + red[1] + red[2] + red[3];
    const float nrm = sqrtf(total);
    const float inv = 1.0f / fmaxf(nrm, KEPS);
    unsigned r = 0;
    r = __builtin_amdgcn_cvt_pk_fp8_f32(v.x * inv, v.y * inv, r, 0);
    r = __builtin_amdgcn_cvt_pk_fp8_f32(v.z * inv, v.w * inv, r, 1);
    ((unsigned*)(xq + (size_t)row * D))[t] = r;
    if (t == 0) {
        norms[row] = nrm;
        best[row] = 0ull;                    // any real packed key beats 0
    }
    if (row < 256 && t == 1) psum[row * 16] = 0.0f;   // cache-line-padded partials
}

__device__ __forceinline__ unsigned long long pack_key(float v, unsigned idx)
{
    unsigned ub = __float_as_uint(v);
    ub = (ub & 0x80000000u) ? ~ub : (ub | 0x80000000u); // monotonic map
    return ((unsigned long long)ub << 32) | (unsigned long long)(~idx);
}

// ---------------- 2) x x^T triangular fp8 GEMM, dbuf LDS, 4 blocks/CU -------
// ROUND-7: round-0 structure (T1 swizzle REMOVED — measured −4%: GEMM 320->335,
// FETCH up), with ONE delta vs the measured-404µs round-0 baseline:
// MFMA 16x16x32_fp8 -> 32x32x16_fp8. Same FLOPs, same ds_read bytes/count,
// but HALF the MFMA instruction count per wave-K-step (16 vs 32) and a +7%
// pipe ceiling (2190 vs 2047 TF µbench). We are stall/issue-bound at the
// barrier (MfmaUtil 35% vs LDS-bank arithmetic predicting ~60% if pipelined),
// so fewer, fatter MFMA issues relieve the contended resource.
// Spill-risk note: rounds 1-4 spills were specific to mfma_scale's i32x8
// operands. Here operands are i64 (2 VGPR) and acc = 4 x f32x16 = 64 floats,
// identical total to round-0's 16 x f32x4. (256,4) kept: demand ~60 arch +
// 64 acc = 124 <= 128 budget, as round-0 proved.
// C/D layout 32x32 (round-1 harness-verified, shape-determined):
// col = lane&31, row = (reg&3) + 8*(reg>>2) + 4*(lane>>5).
// A/B fragment (32x32x16): lane l holds row l&31, k-bytes [(l>>5)*8, +8) of
// the 16B k-slice; 4 k-slices per BK=64. Same 16B-chunk XOR swizzle:
// stored chunk c of row r holds global chunk c ^ psw(r), psw=(r^(r>>2))&3;
// reader fetches chunk ks^psw (psw reduces to (r5^(r5>>2))&3, multiples of
// 32 drop out).
__global__ __launch_bounds__(256, 4) void k_gemm_argmax(
    const uchar* __restrict__ xq, unsigned long long* __restrict__ best,
    int T)
{
    // triangular mapping: p -> (by, bx), bx >= by
    const int p = blockIdx.x;
    const float tf = (float)T + 0.5f;
    int by = (int)(tf - sqrtf(tf * tf - 2.0f * (float)p));
    while (by > 0 && p < by * T - by * (by - 1) / 2) --by;
    while (p >= (by + 1) * T - (by + 1) * by / 2) ++by;
    const int bx = by + (p - (by * T - by * (by - 1) / 2));

    __shared__ uchar lds[2][(BM + BN) * BK];   // 2 x 16 KiB
    const int t    = threadIdx.x;
    const int lane = t & 63;
    const int wave = t >> 6;
    const int r5   = lane & 31;              // row-within-32
    const int h    = lane >> 5;              // k-half selector
    const int wrow = (wave >> 1) * 64;
    const int wcol = (wave & 1) * 64;
    const int m0   = by * BM;
    const int n0   = bx * BN;

    f32x16 acc[2][2] = {};

    // staging: thread t owns stored chunk c = t (rows 0..63) and c = t + 256
    // (rows 64..127) of each panel; stored col = t&3, global col swizzled.
    const int row_s = t >> 2;
    const int col_s = t & 3;
    const int gsw = (col_s ^ ((row_s ^ (row_s >> 2)) & 3)) * 16;  // byte col
    // note swz(row+64) == swz(row), so the same gsw serves both halves
    const uchar* aP0 = xq + (size_t)(m0 + row_s) * 1024 + gsw;
    const uchar* bP0 = xq + (size_t)(n0 + row_s) * 1024 + gsw;
    const uchar* aP1 = aP0 + 64 * 1024;
    const uchar* bP1 = bP0 + 64 * 1024;
    const int l16 = t * 16;

#define STAGE(buf, koff)                                                              \
    do {                                                                              \
        __builtin_amdgcn_global_load_lds(                                             \
            (const __attribute__((address_space(1))) void*)(aP0 + (koff)),            \
            (__attribute__((address_space(3))) void*)(&lds[buf][0] + l16), 16, 0, 0); \
        __builtin_amdgcn_global_load_lds(                                             \
            (const __attribute__((address_space(1))) void*)(aP1 + (koff)),            \
            (__attribute__((address_space(3))) void*)(&lds[buf][4096] + l16), 16, 0, 0); \
        __builtin_amdgcn_global_load_lds(                                             \
            (const __attribute__((address_space(1))) void*)(bP0 + (koff)),            \
            (__attribute__((address_space(3))) void*)(&lds[buf][8192] + l16), 16, 0, 0); \
        __builtin_amdgcn_global_load_lds(                                             \
            (const __attribute__((address_space(1))) void*)(bP1 + (koff)),            \
            (__attribute__((address_space(3))) void*)(&lds[buf][12288] + l16), 16, 0, 0); \
    } while (0)

    STAGE(0, 0);
    __syncthreads();

    // lane-constant LDS read bases; per-ks chunk offset folds to an imm.
    const int psw = (r5 ^ (r5 >> 2)) & 3;
    const int aB0 = (wrow +      r5) * 64;
    const int aB1 = (wrow + 32 + r5) * 64;
    const int bB0 = (wcol +      r5) * 64;
    const int bB1 = (wcol + 32 + r5) * 64;

    #pragma unroll
    for (int kt = 0; kt < 16; ++kt) {
        const int cur = kt & 1;
        if (kt < 15) STAGE(cur ^ 1, (kt + 1) * BK);   // K-advance in pointer
        const uchar* Al = &lds[cur][0];
        const uchar* Bl = &lds[cur][8192];
        #pragma unroll
        for (int ks = 0; ks < 4; ++ks) {     // 4 x K=16 per BK=64
            const int ko = ((ks ^ psw) * 16) + h * 8;  // swizzled 16B chunk
            i64 a0 = *(const i64*)(Al + aB0 + ko);
            i64 a1 = *(const i64*)(Al + aB1 + ko);
            i64 b0 = *(const i64*)(Bl + bB0 + ko);
            i64 b1 = *(const i64*)(Bl + bB1 + ko);
            acc[0][0] = __builtin_amdgcn_mfma_f32_32x32x16_fp8_fp8(a0, b0, acc[0][0], 0, 0, 0);
            acc[0][1] = __builtin_amdgcn_mfma_f32_32x32x16_fp8_fp8(a0, b1, acc[0][1], 0, 0, 0);
            acc[1][0] = __builtin_amdgcn_mfma_f32_32x32x16_fp8_fp8(a1, b0, acc[1][0], 0, 0, 0);
            acc[1][1] = __builtin_amdgcn_mfma_f32_32x32x16_fp8_fp8(a1, b1, acc[1][1], 0, 0, 0);
        }
        __syncthreads();
    }
#undef STAGE

    // ---- row-wise argmax (this wave's 64 rows, over its 64 cols) ----
    // C/D 32x32 layout: col = lane&31, row = (reg&3) + 8*(reg>>2) + 4*(lane>>5)
    #pragma unroll
    for (int i = 0; i < 2; ++i) {
        #pragma unroll
        for (int r = 0; r < 16; ++r) {
            const int rin  = (r & 3) + 8 * (r >> 2) + 4 * h;
            const int grow = m0 + wrow + i * 32 + rin;
            float v = -3.0f; unsigned c = 0xFFFFFFFFu;
            #pragma unroll
            for (int j = 0; j < 2; ++j) {
                const int col = n0 + wcol + j * 32 + r5;
                const float val = acc[i][j][r];
                if (col != grow && (val > v || (val == v && (unsigned)col < c))) {
                    v = val; c = (unsigned)col;
                }
            }
            // reduce across the 32 lanes of this half-wave (same row)
            for (int off = 16; off; off >>= 1) {
                const float    ov = __shfl_xor(v, off);
                const unsigned oc = (unsigned)__shfl_xor((int)c, off);
                if (ov > v || (ov == v && oc < c)) { v = ov; c = oc; }
            }
            if (r5 == 0) atomicMax(best + grow, pack_key(v, c));
        }
    }

    // ---- col-wise argmax (off-diagonal blocks only) ----
    if (bx != by) {
        #pragma unroll
        for (int j = 0; j < 2; ++j) {
            const int gcol = n0 + wcol + j * 32 + r5;
            float v = -3.0f; unsigned c = 0xFFFFFFFFu;
            #pragma unroll
            for (int i = 0; i < 2; ++i) {
                #pragma unroll
                for (int r = 0; r < 16; ++r) {
                    const int grow = m0 + wrow + i * 32
                                   + (r & 3) + 8 * (r >> 2) + 4 * h;
                    const float val = acc[i][j][r];
                    if (val > v || (val == v && (unsigned)grow < c)) {
                        v = val; c = (unsigned)grow;
                    }
                }
            }
            // merge the two half-waves (same col set, different rows)
            {
                const float    ov = __shfl_xor(v, 32);
                const unsigned oc = (unsigned)__shfl_xor((int)c, 32);
                if (ov > v || (ov == v && oc < c)) { v = ov; c = oc; }
            }
            if (h == 0) atomicMax(best + gcol, pack_key(v, c));
        }
    }
}

// ---------------- 3) pairwise distance + log -> 256 padded partials ---------
__global__ __launch_bounds__(256) void k_dist(
    const float* __restrict__ in, const float* __restrict__ norms,
    const unsigned long long* __restrict__ best, float* __restrict__ psum, int D)
{
    const int row = blockIdx.x;
    const int t = threadIdx.x;
    const unsigned long long key = best[row];
    const int nb = (int)(~(unsigned)key);        // recover neighbor index
    const float invi = 1.0f / fmaxf(norms[row], KEPS);
    const float invj = 1.0f / fmaxf(norms[nb], KEPS);
    const float4* xi = (const float4*)(in + (size_t)row * D);
    const float4* xj = (const float4*)(in + (size_t)nb * D);
    const float4 a = xi[t], b = xj[t];
    const float dx = a.x * invi - b.x * invj + KEPS;
    const float dy = a.y * invi - b.y * invj + KEPS;
    const float dz = a.z * invi - b.z * invj + KEPS;
    const float dw = a.w * invi - b.w * invj + KEPS;
    float ss = dx*dx + dy*dy + dz*dz + dw*dw;
    for (int off = 32; off; off >>= 1) ss += __shfl_down(ss, off);
    __shared__ float red[4];
    const int lane = t & 63, wave = t >> 6;
    if (lane == 0) red[wave] = ss;
    __syncthreads();
    if (t == 0) {
        const float tot = red[0] + red[1] + red[2] + red[3];
        // scatter over 256 cache-line-padded slots: 64 atomics/slot, no hotspot
        atomicAdd(psum + (row & 255) * 16, logf(sqrtf(tot) + KEPS));
    }
}

// ---------------- 4) finalize: reduce 256 partials --------------------------
__global__ void k_final(const float* __restrict__ psum, float* __restrict__ out, float invN)
{
    const int t = threadIdx.x;                   // 64 threads
    float s = psum[t * 16] + psum[(t + 64) * 16]
            + psum[(t + 128) * 16] + psum[(t + 192) * 16];
    for (int off = 32; off; off >>= 1) s += __shfl_down(s, off);
    if (t == 0) out[0] = -s * invN;
}

extern "C" void kernel_launch(void* const* d_in, const int* in_sizes, int n_in,
                              void* d_out, int out_size, void* d_ws, size_t ws_size,
                              hipStream_t stream)
{
    const float* in = (const float*)d_in[0];
    const int D = 1024;
    const int N = in_sizes[0] / D;               // 16384

    char* ws = (char*)d_ws;
    uchar* xq = (uchar*)ws;                                      // N*D = 16 MiB
    size_t off = (size_t)N * D;
    float* norms = (float*)(ws + off);           off += (size_t)N * 4;
    unsigned long long* best = (unsigned long long*)(ws + off); off += (size_t)N * 8;
    float* psum = (float*)(ws + off);            // 256 slots x 16 floats
    float* out = (float*)d_out;

    k_normalize<<<N, 256, 0, stream>>>(in, xq, norms, best, psum, D);
    const int T = N / BM;                        // 128 tiles per dim
    const int P = T * (T + 1) / 2;               // 8256 upper-tri blocks
    k_gemm_argmax<<<P, 256, 0, stream>>>(xq, best, T);
    k_dist<<<N, 256, 0, stream>>>(in, norms, best, psum, D);
    k_final<<<1, 64, 0, stream>>>(psum, out, 1.0f / (float)N);
}

// Round 8
// 394.684 us; speedup vs baseline: 1.1904x; 1.1904x over previous
//
#include <hip/hip_runtime.h>

typedef float f32x4 __attribute__((ext_vector_type(4)));
typedef unsigned char uchar;
typedef long i64;

#define KEPS 1e-8f
#define BM 128
#define BN 128
#define BK 64    // fp8 bytes == elements; 16 K-iterations over D=1024

// ---------------- 1) row L2-normalize: fp32 norms + fp8 e4m3 copy -----------
__global__ __launch_bounds__(256) void k_normalize(
    const float* __restrict__ in, uchar* __restrict__ xq,
    float* __restrict__ norms, unsigned long long* __restrict__ best,
    float* __restrict__ psum, int D)
{
    const int row = blockIdx.x;
    const int t = threadIdx.x;
    const float4* inr = (const float4*)(in + (size_t)row * D);
    float4 v = inr[t];                       // D=1024 -> 256 float4
    float ss = v.x*v.x + v.y*v.y + v.z*v.z + v.w*v.w;
    for (int off = 32; off; off >>= 1) ss += __shfl_down(ss, off);
    __shared__ float red[4];
    const int lane = t & 63, wave = t >> 6;
    if (lane == 0) red[wave] = ss;
    __syncthreads();
    const float total = red[0] + red[1] + red[2] + red[3];
    const float nrm = sqrtf(total);
    const float inv = 1.0f / fmaxf(nrm, KEPS);
    unsigned r = 0;
    r = __builtin_amdgcn_cvt_pk_fp8_f32(v.x * inv, v.y * inv, r, 0);
    r = __builtin_amdgcn_cvt_pk_fp8_f32(v.z * inv, v.w * inv, r, 1);
    ((unsigned*)(xq + (size_t)row * D))[t] = r;
    if (t == 0) {
        norms[row] = nrm;
        best[row] = 0ull;                    // any real packed key beats 0
    }
    if (row < 256 && t == 1) psum[row * 16] = 0.0f;   // cache-line-padded partials
}

__device__ __forceinline__ unsigned long long pack_key(float v, unsigned idx)
{
    unsigned ub = __float_as_uint(v);
    ub = (ub & 0x80000000u) ? ~ub : (ub | 0x80000000u); // monotonic map
    return ((unsigned long long)ub << 32) | (unsigned long long)(~idx);
}

// ---------------- 2) x x^T triangular fp8 GEMM, dbuf LDS, 4 blocks/CU -------
// FINAL (round-8): round-0 restored verbatim — the measured best (404.0 µs
// total, GEMM ~320 µs ≈ 860 TF ≈ 39% of the fp8 µbench ceiling = the
// documented 2-phase/128^2 structural plateau). Exploration record:
//  r1-r4: MX-rate mfma_scale (32x32x64 and 16x16x128, all launch_bounds
//         settings) -> operand-fragment spills (0.2-3 GB scratch), 765-2200µs.
//         Toolchain codegen pathology; abandoned.
//  r5:    256^2 counted-vmcnt triple-buffer pipeline -> clean but 492 µs
//         (96 KiB LDS -> 1 block/CU, 2-wave lockstep, conflicts on path).
//  r6:    T1 XCD swizzle on round-0 -> GEMM 320->335 µs, FETCH up. Removed.
//  r7:    32x32x16 fp8 swap -> GEMM ~400 µs (barrier drain is the bottleneck,
//         not MFMA issue count; longer pipe occupancy hurt scheduling slack).
// BM=BN=128, BK=64, 4 waves in 2x2, each wave owns 64x64 (acc 4x4 of f32x4).
// Double-buffered: 2 x 16 KiB LDS -> 32 KiB/block -> 4 blocks/CU (128 KiB).
// __launch_bounds__(256,4) caps regs at 128/wave (64 AGPR acc + ~60 VGPR) so
// 16 waves/CU co-reside: when one block drains its barrier, three others
// still feed the MFMA pipes (cross-block latency hiding).
// XOR swizzle (row ^ row>>2)&3 at 16B granularity: staging stays
// lane-contiguous (swizzle applied to the *global* column), ds_read_b64
// conflicts reduced to free 2-way.
// Triangular covering bx >= by; row-pass + col-pass (off-diag) covers every
// unordered pair; duplicates harmless under idempotent atomicMax.
__global__ __launch_bounds__(256, 4) void k_gemm_argmax(
    const uchar* __restrict__ xq, unsigned long long* __restrict__ best,
    int T)
{
    // triangular mapping: p -> (by, bx), bx >= by
    const int p = blockIdx.x;
    const float tf = (float)T + 0.5f;
    int by = (int)(tf - sqrtf(tf * tf - 2.0f * (float)p));
    while (by > 0 && p < by * T - by * (by - 1) / 2) --by;
    while (p >= (by + 1) * T - (by + 1) * by / 2) ++by;
    const int bx = by + (p - (by * T - by * (by - 1) / 2));

    __shared__ uchar lds[2][(BM + BN) * BK];   // 2 x 16 KiB
    const int t    = threadIdx.x;
    const int lane = t & 63;
    const int wave = t >> 6;
    const int quad = lane >> 4;
    const int c16  = lane & 15;
    const int wrow = (wave >> 1) * 64;
    const int wcol = (wave & 1) * 64;
    const int m0   = by * BM;
    const int n0   = bx * BN;

    f32x4 acc[4][4] = {};

    // staging: thread t owns stored chunk c = t (rows 0..63) and c = t + 256
    // (rows 64..127) of each panel; stored col = t&3, global col swizzled.
    const int row_s = t >> 2;
    const int col_s = t & 3;
    const int gsw = (col_s ^ ((row_s ^ (row_s >> 2)) & 3)) * 16;  // byte col
    // note swz(row+64) == swz(row), so the same gsw serves both halves
    const uchar* aP0 = xq + (size_t)(m0 + row_s) * 1024 + gsw;
    const uchar* bP0 = xq + (size_t)(n0 + row_s) * 1024 + gsw;
    const uchar* aP1 = aP0 + 64 * 1024;
    const uchar* bP1 = bP0 + 64 * 1024;
    const int l16 = t * 16;

#define STAGE(buf, koff)                                                              \
    do {                                                                              \
        __builtin_amdgcn_global_load_lds(                                             \
            (const __attribute__((address_space(1))) void*)(aP0 + (koff)),            \
            (__attribute__((address_space(3))) void*)(&lds[buf][0] + l16), 16, 0, 0); \
        __builtin_amdgcn_global_load_lds(                                             \
            (const __attribute__((address_space(1))) void*)(aP1 + (koff)),            \
            (__attribute__((address_space(3))) void*)(&lds[buf][4096] + l16), 16, 0, 0); \
        __builtin_amdgcn_global_load_lds(                                             \
            (const __attribute__((address_space(1))) void*)(bP0 + (koff)),            \
            (__attribute__((address_space(3))) void*)(&lds[buf][8192] + l16), 16, 0, 0); \
        __builtin_amdgcn_global_load_lds(                                             \
            (const __attribute__((address_space(1))) void*)(bP1 + (koff)),            \
            (__attribute__((address_space(3))) void*)(&lds[buf][12288] + l16), 16, 0, 0); \
    } while (0)

    STAGE(0, 0);
    __syncthreads();

    #pragma unroll
    for (int kt = 0; kt < 16; ++kt) {
        const int cur = kt & 1;
        if (kt < 15) STAGE(cur ^ 1, (kt + 1) * BK);   // K-advance in pointer
        const uchar* Al = &lds[cur][0];
        const uchar* Bl = &lds[cur][8192];
        #pragma unroll
        for (int ks = 0; ks < 2; ++ks) {     // 2 x K=32 per BK=64
            i64 a[4], b[4];
            const int ccol = ks * 2 + (quad >> 1);    // 16B chunk col
            const int inner = (quad & 1) * 8;
            #pragma unroll
            for (int i = 0; i < 4; ++i) {
                const int row = wrow + i * 16 + c16;
                a[i] = *(const i64*)(Al + row * 64 +
                        ((ccol ^ ((row ^ (row >> 2)) & 3)) * 16) + inner);
            }
            #pragma unroll
            for (int j = 0; j < 4; ++j) {
                const int row = wcol + j * 16 + c16;
                b[j] = *(const i64*)(Bl + row * 64 +
                        ((ccol ^ ((row ^ (row >> 2)) & 3)) * 16) + inner);
            }
            #pragma unroll
            for (int i = 0; i < 4; ++i)
                #pragma unroll
                for (int j = 0; j < 4; ++j)
                    acc[i][j] = __builtin_amdgcn_mfma_f32_16x16x32_fp8_fp8(
                        a[i], b[j], acc[i][j], 0, 0, 0);
        }
        __syncthreads();
    }
#undef STAGE

    // ---- row-wise argmax (this wave's 64 rows, over its 64 cols) ----
    // C/D layout (m89-verified, dtype-independent): col = lane&15, row = quad*4 + reg.
    #pragma unroll
    for (int i = 0; i < 4; ++i) {
        #pragma unroll
        for (int r = 0; r < 4; ++r) {
            const int grow = m0 + wrow + i * 16 + quad * 4 + r;
            float v = -3.0f; unsigned c = 0xFFFFFFFFu;
            #pragma unroll
            for (int j = 0; j < 4; ++j) {
                const int col = n0 + wcol + j * 16 + c16;
                const float val = acc[i][j][r];
                if (col != grow && (val > v || (val == v && (unsigned)col < c))) {
                    v = val; c = (unsigned)col;
                }
            }
            // reduce across the quad's 16 lanes (one row lives in one quad)
            for (int off = 8; off; off >>= 1) {
                const float    ov = __shfl_xor(v, off);
                const unsigned oc = (unsigned)__shfl_xor((int)c, off);
                if (ov > v || (ov == v && oc < c)) { v = ov; c = oc; }
            }
            if (c16 == 0) atomicMax(best + grow, pack_key(v, c));
        }
    }

    // ---- col-wise argmax (off-diagonal blocks only) ----
    if (bx != by) {
        #pragma unroll
        for (int j = 0; j < 4; ++j) {
            const int gcol = n0 + wcol + j * 16 + c16;
            float v = -3.0f; unsigned c = 0xFFFFFFFFu;
            #pragma unroll
            for (int i = 0; i < 4; ++i) {
                #pragma unroll
                for (int r = 0; r < 4; ++r) {
                    const int grow = m0 + wrow + i * 16 + quad * 4 + r;
                    const float val = acc[i][j][r];
                    if (val > v || (val == v && (unsigned)grow < c)) {
                        v = val; c = (unsigned)grow;
                    }
                }
            }
            // reduce across the 4 quads (lanes sharing c16): xor 16, 32
            for (int off = 32; off >= 16; off >>= 1) {
                const float    ov = __shfl_xor(v, off);
                const unsigned oc = (unsigned)__shfl_xor((int)c, off);
                if (ov > v || (ov == v && oc < c)) { v = ov; c = oc; }
            }
            if (quad == 0) atomicMax(best + gcol, pack_key(v, c));
        }
    }
}

// ---------------- 3) pairwise distance + log -> 256 padded partials ---------
__global__ __launch_bounds__(256) void k_dist(
    const float* __restrict__ in, const float* __restrict__ norms,
    const unsigned long long* __restrict__ best, float* __restrict__ psum, int D)
{
    const int row = blockIdx.x;
    const int t = threadIdx.x;
    const unsigned long long key = best[row];
    const int nb = (int)(~(unsigned)key);        // recover neighbor index
    const float invi = 1.0f / fmaxf(norms[row], KEPS);
    const float invj = 1.0f / fmaxf(norms[nb], KEPS);
    const float4* xi = (const float4*)(in + (size_t)row * D);
    const float4* xj = (const float4*)(in + (size_t)nb * D);
    const float4 a = xi[t], b = xj[t];
    const float dx = a.x * invi - b.x * invj + KEPS;
    const float dy = a.y * invi - b.y * invj + KEPS;
    const float dz = a.z * invi - b.z * invj + KEPS;
    const float dw = a.w * invi - b.w * invj + KEPS;
    float ss = dx*dx + dy*dy + dz*dz + dw*dw;
    for (int off = 32; off; off >>= 1) ss += __shfl_down(ss, off);
    __shared__ float red[4];
    const int lane = t & 63, wave = t >> 6;
    if (lane == 0) red[wave] = ss;
    __syncthreads();
    if (t == 0) {
        const float tot = red[0] + red[1] + red[2] + red[3];
        // scatter over 256 cache-line-padded slots: 64 atomics/slot, no hotspot
        atomicAdd(psum + (row & 255) * 16, logf(sqrtf(tot) + KEPS));
    }
}

// ---------------- 4) finalize: reduce 256 partials --------------------------
__global__ void k_final(const float* __restrict__ psum, float* __restrict__ out, float invN)
{
    const int t = threadIdx.x;                   // 64 threads
    float s = psum[t * 16] + psum[(t + 64) * 16]
            + psum[(t + 128) * 16] + psum[(t + 192) * 16];
    for (int off = 32; off; off >>= 1) s += __shfl_down(s, off);
    if (t == 0) out[0] = -s * invN;
}

extern "C" void kernel_launch(void* const* d_in, const int* in_sizes, int n_in,
                              void* d_out, int out_size, void* d_ws, size_t ws_size,
                              hipStream_t stream)
{
    const float* in = (const float*)d_in[0];
    const int D = 1024;
    const int N = in_sizes[0] / D;               // 16384

    char* ws = (char*)d_ws;
    uchar* xq = (uchar*)ws;                                      // N*D = 16 MiB
    size_t off = (size_t)N * D;
    float* norms = (float*)(ws + off);           off += (size_t)N * 4;
    unsigned long long* best = (unsigned long long*)(ws + off); off += (size_t)N * 8;
    float* psum = (float*)(ws + off);            // 256 slots x 16 floats
    float* out = (float*)d_out;

    k_normalize<<<N, 256, 0, stream>>>(in, xq, norms, best, psum, D);
    const int T = N / BM;                        // 128 tiles per dim
    const int P = T * (T + 1) / 2;               // 8256 upper-tri blocks
    k_gemm_argmax<<<P, 256, 0, stream>>>(xq, best, T);
    k_dist<<<N, 256, 0, stream>>>(in, norms, best, psum, D);
    k_final<<<1, 64, 0, stream>>>(psum, out, 1.0f / (float)N);
}